// Round 12
// baseline (624.999 us; speedup 1.0000x reference)
//
#include <hip/hip_runtime.h>
#include <math.h>

#define BB 32
#define NN 1025
#define DDIM 768
#define HH 12
#define DHD 64
#define KC 257
#define CPBH 32

#define BT_K 320
#define BT_N 1088
#define SCALE_LOG2E 0.18033688011112042f  /* 0.125 * log2(e) */

typedef unsigned int u32;
typedef unsigned short u16;
typedef unsigned char u8;
typedef __attribute__((ext_vector_type(8))) short s8v;
typedef __attribute__((ext_vector_type(4))) float f4v;

__device__ __forceinline__ u16 f2bf(float f) {
  union { float f; u32 u; } v; v.f = f;
  return (u16)((v.u + 0x7fffu + ((v.u >> 16) & 1u)) >> 16);
}
__device__ __forceinline__ float bf2f(u16 h) {
  union { u32 u; float f; } v; v.u = ((u32)h) << 16;
  return v.f;
}
__device__ __forceinline__ void gload16(const u16* g, u16* l) {
  __builtin_amdgcn_global_load_lds((const __attribute__((address_space(1))) void*)g,
                                   (__attribute__((address_space(3))) void*)l, 16, 0, 0);
}

// ---------------------------------------------------------------------------
// fp32 -> bf16 cast (8 elements/thread)
// ---------------------------------------------------------------------------
__global__ __launch_bounds__(256) void cast_bf16_kernel(const float* __restrict__ s,
                                                        u16* __restrict__ d, int n8) {
  const int i = blockIdx.x * 256 + threadIdx.x;
  if (i >= n8) return;
  const float4 f0 = ((const float4*)s)[2 * i];
  const float4 f1 = ((const float4*)s)[2 * i + 1];
  s8v o;
  o[0] = (short)f2bf(f0.x); o[1] = (short)f2bf(f0.y);
  o[2] = (short)f2bf(f0.z); o[3] = (short)f2bf(f0.w);
  o[4] = (short)f2bf(f1.x); o[5] = (short)f2bf(f1.y);
  o[6] = (short)f2bf(f1.z); o[7] = (short)f2bf(f1.w);
  *(s8v*)&d[8 * (size_t)i] = o;
}

// fp32 -> (bf16 hi, bf16 lo) split cast
__global__ __launch_bounds__(256) void split_bf16_kernel(const float* __restrict__ s,
                                                         u16* __restrict__ dh,
                                                         u16* __restrict__ dl, int n8) {
  const int i = blockIdx.x * 256 + threadIdx.x;
  if (i >= n8) return;
  s8v oh, ol;
#pragma unroll
  for (int j = 0; j < 8; j++) {
    const float f = s[8 * (size_t)i + j];
    const u16 hb = f2bf(f);
    oh[j] = (short)hb;
    ol[j] = (short)f2bf(f - bf2f(hb));
  }
  *(s8v*)&dh[8 * (size_t)i] = oh;
  *(s8v*)&dl[8 * (size_t)i] = ol;
}

// ---------------------------------------------------------------------------
// tiled softmax pooling -> ctx [B, KC, D] (bf16 out). v2 (round 11, proven
// as part of -29us): 256 thr (4 waves, one kk-tile per wave), float4 reads.
// ---------------------------------------------------------------------------
__global__ __launch_bounds__(256) void pool_ctx_kernel(const float* __restrict__ x,
                                                       const float* __restrict__ wlog,
                                                       u16* __restrict__ ctx) {
  const int w = threadIdx.x >> 6, lane = threadIdx.x & 63;
  const int bid = blockIdx.x;
  const int b = bid / 65;
  const int kk = (bid % 65) * 4 + w;
  if (kk >= KC) return;
  const float* xb = x + (size_t)b * NN * DDIM;
  u16* cout = ctx + ((size_t)b * KC + kk) * DDIM;
  if (kk == 0) {
#pragma unroll
    for (int u = lane; u < 192; u += 64) {
      const float4 f = ((const float4*)xb)[u];
      ushort4 o = {f2bf(f.x), f2bf(f.y), f2bf(f.z), f2bf(f.w)};
      *(ushort4*)&cout[u * 4] = o;
    }
    return;
  }
  const int t = kk - 1;
  const int gy = t >> 4, gx = t & 15;
  const int r0 = 1 + gy * 64 + gx * 2;
  const float* xr0 = xb + (size_t)r0 * DDIM;
  float s0 = 0.f, s1 = 0.f, s2 = 0.f, s3 = 0.f;
#pragma unroll
  for (int u = lane; u < 192; u += 64) {
    const float4 a = ((const float4*)xr0)[u];
    const float4 bq = ((const float4*)(xr0 + DDIM))[u];
    const float4 c = ((const float4*)(xr0 + 32 * DDIM))[u];
    const float4 d = ((const float4*)(xr0 + 33 * DDIM))[u];
    const float4 wv = ((const float4*)wlog)[u];
    s0 = fmaf(a.x, wv.x, fmaf(a.y, wv.y, fmaf(a.z, wv.z, fmaf(a.w, wv.w, s0))));
    s1 = fmaf(bq.x, wv.x, fmaf(bq.y, wv.y, fmaf(bq.z, wv.z, fmaf(bq.w, wv.w, s1))));
    s2 = fmaf(c.x, wv.x, fmaf(c.y, wv.y, fmaf(c.z, wv.z, fmaf(c.w, wv.w, s2))));
    s3 = fmaf(d.x, wv.x, fmaf(d.y, wv.y, fmaf(d.z, wv.z, fmaf(d.w, wv.w, s3))));
  }
#pragma unroll
  for (int off = 32; off; off >>= 1) {
    s0 += __shfl_xor(s0, off);
    s1 += __shfl_xor(s1, off);
    s2 += __shfl_xor(s2, off);
    s3 += __shfl_xor(s3, off);
  }
  const float m = fmaxf(fmaxf(s0, s1), fmaxf(s2, s3));
  float e0 = expf(s0 - m), e1 = expf(s1 - m), e2 = expf(s2 - m), e3 = expf(s3 - m);
  const float inv = 1.0f / (e0 + e1 + e2 + e3);
  e0 *= inv; e1 *= inv; e2 *= inv; e3 *= inv;
#pragma unroll
  for (int u = lane; u < 192; u += 64) {
    const float4 a = ((const float4*)xr0)[u];
    const float4 bq = ((const float4*)(xr0 + DDIM))[u];
    const float4 c = ((const float4*)(xr0 + 32 * DDIM))[u];
    const float4 d = ((const float4*)(xr0 + 33 * DDIM))[u];
    ushort4 o;
    o.x = f2bf(e0 * a.x + e1 * bq.x + e2 * c.x + e3 * d.x);
    o.y = f2bf(e0 * a.y + e1 * bq.y + e2 * c.y + e3 * d.y);
    o.z = f2bf(e0 * a.z + e1 * bq.z + e2 * c.z + e3 * d.z);
    o.w = f2bf(e0 * a.w + e1 * bq.w + e2 * c.w + e3 * d.w);
    *(ushort4*)&cout[u * 4] = o;
  }
}

// ---------------------------------------------------------------------------
// CPB bias, transposed+padded layout: biasT[h][k=320][n=1088] fp32,
// value = (mlp(feats)+b2)*mask*log2e for valid (k<257,n<1025), else -1e30.
// Thread idx = k*1088 + n -> coalesced stores.
// ---------------------------------------------------------------------------
__global__ __launch_bounds__(256) void cpb_biasT_kernel(const float* __restrict__ feats,
                                                        const float* __restrict__ mask,
                                                        const float* __restrict__ w1,
                                                        const float* __restrict__ b1,
                                                        const float* __restrict__ w2,
                                                        const float* __restrict__ b2,
                                                        float* __restrict__ biasT) {
  const int idx = blockIdx.x * 256 + threadIdx.x;
  if (idx >= BT_K * BT_N) return;
  const int k = idx / BT_N;
  const int n = idx - k * BT_N;
  const bool valid = (k < KC) && (n < NN);
  float out[HH];
  if (valid) {
    const float2 f = *(const float2*)&feats[2 * ((size_t)n * KC + k)];
    const float mk = mask[(size_t)n * KC + k] * 1.4426950408889634f;
    float hb[CPBH];
#pragma unroll
    for (int j = 0; j < CPBH; j++) {
      const float tv = fmaf(w1[2 * j], f.x, fmaf(w1[2 * j + 1], f.y, b1[j]));
      hb[j] = 0.5f * tv * (1.0f + erff(tv * 0.70710678118654752f));
    }
#pragma unroll
    for (int h = 0; h < HH; h++) {
      float acc = b2[h];
#pragma unroll
      for (int j = 0; j < CPBH; j++) acc = fmaf(hb[j], w2[h * CPBH + j], acc);
      out[h] = acc * mk;
    }
  } else {
#pragma unroll
    for (int h = 0; h < HH; h++) out[h] = -1.0e30f;
  }
#pragma unroll
  for (int h = 0; h < HH; h++) biasT[(size_t)h * BT_K * BT_N + idx] = out[h];
}

// ---------------------------------------------------------------------------
// bf16 MFMA GEMM, single-buffered (round-10 proven config; round-11 dbuf
// A/B: 2x LDS cut occupancy 38->29%, dur +10us -> m99/m100 verdict holds,
// implicit wave overlap beats explicit dbuf here). Split = 128x64, VGPR 64.
// 1-D grid, M-panel-major order, bijective XCD chunk swizzle.
// ---------------------------------------------------------------------------
template <int SPLIT, int WRITE_BF16, int ADD_BIAS>
__global__ __launch_bounds__(256) void gemm_mfma(const u16* __restrict__ Ah,
                                                 const u16* __restrict__ Al,
                                                 const u16* __restrict__ Bh,
                                                 const u16* __restrict__ Bl,
                                                 const float* __restrict__ bias,
                                                 float* __restrict__ Cf,
                                                 u16* __restrict__ Cb, int M, int Nout,
                                                 int nNB) {
  constexpr int BN = SPLIT ? 64 : 128;
  constexpr int NTI = SPLIT ? 2 : 4;
  __shared__ u16 AhL[128 * 32];
  __shared__ u16 BhL[BN * 32];
  __shared__ u16 AlL[SPLIT ? 128 * 32 : 8];
  __shared__ u16 BlL[SPLIT ? BN * 32 : 8];
  const int tid = threadIdx.x;
  const int w = tid >> 6, l = tid & 63;
  const int lane16 = l & 15, quad = l >> 4;
  // ---- bijective XCD chunk swizzle ----
  const int nwg = (int)gridDim.x;
  const int q8 = nwg >> 3, r8 = nwg & 7;
  const int xcd = (int)blockIdx.x & 7, idx8 = (int)blockIdx.x >> 3;
  const int orig = (xcd < r8 ? xcd * (q8 + 1) : r8 * (q8 + 1) + (xcd - r8) * q8) + idx8;
  const int mb = orig / nNB;
  const int nb = orig - mb * nNB;
  const int m0 = mb * 128, n0 = nb * BN;
  const int sr = l >> 2, sc = (l & 3) * 8;
  const int ar0 = min(m0 + w * 32 + sr, M - 1);
  const int ar1 = min(m0 + w * 32 + 16 + sr, M - 1);
  const u16* ap0 = Ah + (size_t)ar0 * DDIM + sc;
  const u16* ap1 = Ah + (size_t)ar1 * DDIM + sc;
  const u16* alp0 = nullptr; const u16* alp1 = nullptr;
  const u16* bp0 = nullptr; const u16* bp1 = nullptr; const u16* blp0 = nullptr;
  if constexpr (SPLIT) {
    alp0 = Al + (size_t)ar0 * DDIM + sc;
    alp1 = Al + (size_t)ar1 * DDIM + sc;
    bp0 = Bh + (size_t)(n0 + w * 16 + sr) * DDIM + sc;
    blp0 = Bl + (size_t)(n0 + w * 16 + sr) * DDIM + sc;
  } else {
    bp0 = Bh + (size_t)(n0 + w * 32 + sr) * DDIM + sc;
    bp1 = Bh + (size_t)(n0 + w * 32 + 16 + sr) * DDIM + sc;
  }
  f4v acc[4][NTI];
#pragma unroll
  for (int mt = 0; mt < 4; mt++)
#pragma unroll
    for (int nt = 0; nt < NTI; nt++) acc[mt][nt] = (f4v){0.f, 0.f, 0.f, 0.f};
  const int mh = (w & 1) * 64;
  const int nh = (w >> 1) * (SPLIT ? 32 : 64);

  for (int k0 = 0; k0 < DDIM; k0 += 32) {
    __syncthreads();
    gload16(ap0 + k0, &AhL[(w * 32) * 32]);
    gload16(ap1 + k0, &AhL[(w * 32 + 16) * 32]);
    if constexpr (SPLIT) {
      gload16(alp0 + k0, &AlL[(w * 32) * 32]);
      gload16(alp1 + k0, &AlL[(w * 32 + 16) * 32]);
      gload16(bp0 + k0, &BhL[(w * 16) * 32]);
      gload16(blp0 + k0, &BlL[(w * 16) * 32]);
    } else {
      gload16(bp0 + k0, &BhL[(w * 32) * 32]);
      gload16(bp1 + k0, &BhL[(w * 32 + 16) * 32]);
    }
    __syncthreads();
    s8v af[4], afl[4];
#pragma unroll
    for (int mt = 0; mt < 4; mt++) {
      af[mt] = *(const s8v*)&AhL[(mh + mt * 16 + lane16) * 32 + quad * 8];
      if constexpr (SPLIT)
        afl[mt] = *(const s8v*)&AlL[(mh + mt * 16 + lane16) * 32 + quad * 8];
    }
#pragma unroll
    for (int nt = 0; nt < NTI; nt++) {
      const s8v bfh = *(const s8v*)&BhL[(nh + nt * 16 + lane16) * 32 + quad * 8];
      s8v bfl;
      if constexpr (SPLIT)
        bfl = *(const s8v*)&BlL[(nh + nt * 16 + lane16) * 32 + quad * 8];
#pragma unroll
      for (int mt = 0; mt < 4; mt++) {
        acc[mt][nt] = __builtin_amdgcn_mfma_f32_16x16x32_bf16(af[mt], bfh, acc[mt][nt], 0, 0, 0);
        if constexpr (SPLIT) {
          acc[mt][nt] = __builtin_amdgcn_mfma_f32_16x16x32_bf16(afl[mt], bfh, acc[mt][nt], 0, 0, 0);
          acc[mt][nt] = __builtin_amdgcn_mfma_f32_16x16x32_bf16(af[mt], bfl, acc[mt][nt], 0, 0, 0);
        }
      }
    }
  }
#pragma unroll
  for (int mt = 0; mt < 4; mt++)
#pragma unroll
    for (int nt = 0; nt < NTI; nt++)
#pragma unroll
      for (int r = 0; r < 4; r++) {
        const int row = m0 + mh + mt * 16 + quad * 4 + r;
        if (row < M) {
          const int col = n0 + nh + nt * 16 + lane16;
          float v = acc[mt][nt][r];
          if (ADD_BIAS) v += bias[col];
          if (WRITE_BF16) Cb[(size_t)row * Nout + col] = f2bf(v);
          else Cf[(size_t)row * Nout + col] = v;
        }
      }
}

// ---------------------------------------------------------------------------
// V transpose: kvb V-half [b][k][h*64+c] -> vt [b][h][c][k pad 320] bf16,
// zero-filled for k >= 257. Coalesced b128 reads, 16B-run scatter writes.
// ---------------------------------------------------------------------------
__global__ __launch_bounds__(256) void transpose_v_kernel(const u16* __restrict__ kvb,
                                                          u16* __restrict__ vt) {
  const int bh = blockIdx.x;
  const int b = bh / HH, h = bh % HH;
  const int tid = threadIdx.x;
  const int kk = tid >> 3;           // 0..31
  const int c0 = (tid & 7) * 8;      // 0..56
  u16* dbase = vt + (((size_t)b * HH + h) * 64 + c0) * BT_K;
#pragma unroll
  for (int ch = 0; ch < 10; ch++) {
    const int k = ch * 32 + kk;
    s8v v = {0, 0, 0, 0, 0, 0, 0, 0};
    if (k < KC)
      v = *(const s8v*)(kvb + ((size_t)b * KC + k) * (2 * DDIM) + DDIM + h * DHD + c0);
#pragma unroll
    for (int j = 0; j < 8; j++) dbase[(size_t)j * BT_K + k] = (u16)v[j];
  }
}

// ---------------------------------------------------------------------------
// MFMA attention v7 (round 10, proven): chunked K/V LDS staging via
// global_load_lds, XOR source-pre-swizzle, h-OUTER bijective XCD decode
// (keeps per-head biasT slice L2-resident).
// ---------------------------------------------------------------------------
#define PLS 72

__global__ __launch_bounds__(256, 4) void attn_mfma(const u16* qb,
                                                    const u16* __restrict__ kvb,
                                                    const u16* __restrict__ vt,
                                                    const float* __restrict__ biasT,
                                                    u16* oh, u16* __restrict__ ol) {
  __shared__ u16 KV[2][64 * 64];     // 16,384 B staging (K phase, then V phase)
  __shared__ u16 PL[4][16 * PLS];    //  9,216 B per-wave P tiles
  const int tid = threadIdx.x;
  const int w = tid >> 6, l = tid & 63;
  const int lane16 = l & 15, quad = l >> 4;
  const int r7 = lane16 & 7;
  // ---- bijective XCD chunk swizzle, h-OUTER decode (b inner, nb fastest) ----
  const int nwg = (int)gridDim.x;
  const int q8 = nwg >> 3, r8 = nwg & 7;
  const int xcd = (int)blockIdx.x & 7, idx8 = (int)blockIdx.x >> 3;
  const int orig = (xcd < r8 ? xcd * (q8 + 1) : r8 * (q8 + 1) + (xcd - r8) * q8) + idx8;
  const int nb = orig % 17;
  const int hb = orig / 17;
  const int b = hb % BB, h = hb / BB;
  const int n_base = nb * 64 + w * 16;

  const u16* kvb_bh = kvb + (size_t)b * KC * (2 * DDIM) + h * DHD;
  const u16* vt_bh = vt + (((size_t)b * HH + h) * 64) * BT_K;

  // staging lane geometry: each 1KB wave-load covers 8 rows x 128B;
  // lane l -> row +(l>>3), 16B-unit (l&7); source col16 XOR-swizzled by row&7.
  const int srow = l >> 3;                    // 0..7
  const int scol = ((l & 7) ^ srow) * 8;      // elem offset of swizzled 16B unit
  const int rbase = w * 16;                   // this wave's 16 rows of each chunk

  // ---- stage K chunk 0 ----
#pragma unroll
  for (int j = 0; j < 2; j++) {
    const int krow = min(rbase + j * 8 + srow, KC - 1);
    gload16(kvb_bh + (size_t)krow * (2 * DDIM) + scol, &KV[0][(rbase + j * 8) * 64]);
  }

  // ---- q fragments ----
  const int qrow = min(n_base + lane16, NN - 1);
  const u16* qp = qb + ((size_t)b * NN + qrow) * DDIM + h * DHD + quad * 8;
  const s8v qf0 = *(const s8v*)qp;
  const s8v qf1 = *(const s8v*)(qp + 32);

  __syncthreads();  // K ch0 staged

  // ---- S = QK^T fused with bias (log2 domain); K from LDS chunks ----
  f4v S[17];
  const float* bT = biasT + (size_t)h * BT_K * BT_N + (size_t)(n_base + quad * 4);
  float mx[4] = {-3.0e38f, -3.0e38f, -3.0e38f, -3.0e38f};
#pragma unroll
  for (int ch = 0; ch < 5; ch++) {
    if (ch < 4) {
#pragma unroll
      for (int j = 0; j < 2; j++) {
        const int krow = min((ch + 1) * 64 + rbase + j * 8 + srow, KC - 1);
        gload16(kvb_bh + (size_t)krow * (2 * DDIM) + scol,
                &KV[(ch + 1) & 1][(rbase + j * 8) * 64]);
      }
    }
    const u16* KL = KV[ch & 1];
#pragma unroll
    for (int tt = 0; tt < 4; tt++) {
      const int t = ch * 4 + tt;
      if (t < 17) {
        const int row = tt * 16 + lane16;
        const s8v kf0 = *(const s8v*)&KL[row * 64 + ((quad ^ r7) * 8)];
        const s8v kf1 = *(const s8v*)&KL[row * 64 + (((quad + 4) ^ r7) * 8)];
        f4v z = {0.f, 0.f, 0.f, 0.f};
        z = __builtin_amdgcn_mfma_f32_16x16x32_bf16(qf0, kf0, z, 0, 0, 0);
        z = __builtin_amdgcn_mfma_f32_16x16x32_bf16(qf1, kf1, z, 0, 0, 0);
        const float4 bv = *(const float4*)&bT[(size_t)(t * 16 + lane16) * BT_N];
        S[t][0] = fmaf(z[0], SCALE_LOG2E, bv.x);
        S[t][1] = fmaf(z[1], SCALE_LOG2E, bv.y);
        S[t][2] = fmaf(z[2], SCALE_LOG2E, bv.z);
        S[t][3] = fmaf(z[3], SCALE_LOG2E, bv.w);
#pragma unroll
        for (int r = 0; r < 4; r++) mx[r] = fmaxf(mx[r], S[t][r]);
      }
    }
    __syncthreads();
  }

  // ---- prefetch V chunk 0 (hides under softmax VALU, T14) ----
#pragma unroll
  for (int j = 0; j < 2; j++) {
    const int c = rbase + j * 8 + srow;
    gload16(vt_bh + (size_t)c * BT_K + scol, &KV[0][(rbase + j * 8) * 64]);
  }

  // ---- softmax (log2 domain, deferred normalization) ----
#pragma unroll
  for (int r = 0; r < 4; r++) {
    mx[r] = fmaxf(mx[r], __shfl_xor(mx[r], 1));
    mx[r] = fmaxf(mx[r], __shfl_xor(mx[r], 2));
    mx[r] = fmaxf(mx[r], __shfl_xor(mx[r], 4));
    mx[r] = fmaxf(mx[r], __shfl_xor(mx[r], 8));
  }
  float sm[4] = {0.f, 0.f, 0.f, 0.f};
#pragma unroll
  for (int t = 0; t < 17; t++)
#pragma unroll
    for (int r = 0; r < 4; r++) {
      const float p = exp2f(S[t][r] - mx[r]);  // unnormalized
      S[t][r] = p;
      sm[r] += p;
    }
#pragma unroll
  for (int r = 0; r < 4; r++) {
    sm[r] += __shfl_xor(sm[r], 1);
    sm[r] += __shfl_xor(sm[r], 2);
    sm[r] += __shfl_xor(sm[r], 4);
    sm[r] += __shfl_xor(sm[r], 8);
    sm[r] = 1.0f / sm[r];
  }

  f4v O[4];
#pragma unroll
  for (int nt = 0; nt < 4; nt++) O[nt] = (f4v){0.f, 0.f, 0.f, 0.f};

  __syncthreads();  // V ch0 staged

  u16* PLw = PL[w];
#pragma unroll
  for (int ch = 0; ch < 5; ch++) {
    if (ch < 4) {
#pragma unroll
      for (int j = 0; j < 2; j++) {
        const int c = rbase + j * 8 + srow;
        gload16(vt_bh + (size_t)c * BT_K + (ch + 1) * 64 + scol,
                &KV[(ch + 1) & 1][(rbase + j * 8) * 64]);
      }
    }
#pragma unroll
    for (int tt = 0; tt < 4; tt++) {
      const int t = ch * 4 + tt;
#pragma unroll
      for (int r = 0; r < 4; r++) {
        float pv = 0.f;
        if (t < 17) pv = S[t][r];
        PLw[(quad * 4 + r) * PLS + tt * 16 + lane16] = f2bf(pv);
      }
    }
    const u16* VL = KV[ch & 1];
    // per-wave private PL: within-wave lgkmcnt ordering suffices, no barrier
#pragma unroll
    for (int ks = 0; ks < 2; ks++) {
      const s8v a = *(const s8v*)&PLw[lane16 * PLS + ks * 32 + quad * 8];
#pragma unroll
      for (int nt = 0; nt < 4; nt++) {
        const s8v bfr =
            *(const s8v*)&VL[(nt * 16 + lane16) * 64 + (((ks * 4 + quad) ^ r7) * 8)];
        O[nt] = __builtin_amdgcn_mfma_f32_16x16x32_bf16(a, bfr, O[nt], 0, 0, 0);
      }
    }
    __syncthreads();
  }

  // ---- epilogue: normalize + split-store (hi/lo bf16) ----
#pragma unroll
  for (int nt = 0; nt < 4; nt++)
#pragma unroll
    for (int r = 0; r < 4; r++) {
      const int n = n_base + quad * 4 + r;
      if (n < NN) {
        const size_t idx = ((size_t)b * NN + n) * DDIM + h * DHD + nt * 16 + lane16;
        const float v = O[nt][r] * sm[r];
        const u16 hb2 = f2bf(v);
        oh[idx] = hb2;
        ol[idx] = f2bf(v - bf2f(hb2));
      }
    }
}

// ---------------------------------------------------------------------------
extern "C" void kernel_launch(void* const* d_in, const int* in_sizes, int n_in,
                              void* d_out, int out_size, void* d_ws, size_t ws_size,
                              hipStream_t stream) {
  (void)in_sizes; (void)n_in; (void)out_size; (void)ws_size;
  const float* x    = (const float*)d_in[0];
  const float* wlog = (const float*)d_in[1];
  const float* Wq   = (const float*)d_in[2];
  const float* Wkv  = (const float*)d_in[3];
  const float* Wo   = (const float*)d_in[4];
  const float* bo   = (const float*)d_in[5];
  const float* w1   = (const float*)d_in[6];
  const float* b1   = (const float*)d_in[7];
  const float* w2   = (const float*)d_in[8];
  const float* b2   = (const float*)d_in[9];
  const float* feats = (const float*)d_in[10];
  const float* mask  = (const float*)d_in[11];
  float* out = (float*)d_out;

  u8* p = (u8*)d_ws;
  u16* xb    = (u16*)(p + 0);             // 50,380,800 B (later o_lo)
  u16* ctxb  = (u16*)(p + 50380800);      // 12,632,064
  u16* Wqb   = (u16*)(p + 63012864);      //  1,179,648
  u16* Wkvb  = (u16*)(p + 64192512);      //  2,359,296
  u16* Woh   = (u16*)(p + 66551808);      //  1,179,648
  u16* Wol   = (u16*)(p + 67731456);      //  1,179,648
  u16* qb    = (u16*)(p + 68911104);      // 50,380,800 (later o_hi)
  u16* kvb   = (u16*)(p + 119291904);     // 25,264,128
  u16* vt    = (u16*)(p + 144556032);     // 15,728,640  [B][H][64][320]
  float* biasT = (float*)(p + 160284672); // 16,711,680  [H][320][1088] -> ~177 MB

  const int nx8 = (BB * NN * DDIM) / 8;
  cast_bf16_kernel<<<dim3((nx8 + 255) / 256), dim3(256), 0, stream>>>(x, xb, nx8);
  cast_bf16_kernel<<<dim3(288), dim3(256), 0, stream>>>(Wq, Wqb, (DDIM * DDIM) / 8);
  cast_bf16_kernel<<<dim3(576), dim3(256), 0, stream>>>(Wkv, Wkvb, (2 * DDIM * DDIM) / 8);
  split_bf16_kernel<<<dim3(288), dim3(256), 0, stream>>>(Wo, Woh, Wol, (DDIM * DDIM) / 8);
  pool_ctx_kernel<<<dim3(BB * 65), dim3(256), 0, stream>>>(x, wlog, ctxb);
  cpb_biasT_kernel<<<dim3((BT_K * BT_N) / 256), dim3(256), 0, stream>>>(
      feats, mask, w1, b1, w2, b2, biasT);
  gemm_mfma<0, 1, 0><<<dim3(257 * 6), dim3(256), 0, stream>>>(
      xb, nullptr, Wqb, nullptr, nullptr, nullptr, qb, BB * NN, DDIM, 6);
  gemm_mfma<0, 1, 0><<<dim3(65 * 12), dim3(256), 0, stream>>>(
      ctxb, nullptr, Wkvb, nullptr, nullptr, nullptr, kvb, BB * KC, 2 * DDIM, 12);
  transpose_v_kernel<<<dim3(BB * HH), dim3(256), 0, stream>>>(kvb, vt);
  attn_mfma<<<dim3(17 * HH * BB), dim3(256), 0, stream>>>(qb, kvb, vt, biasT, qb, xb);
  gemm_mfma<1, 0, 1><<<dim3(257 * 12), dim3(256), 0, stream>>>(
      qb, xb, Woh, Wol, bo, out, nullptr, BB * NN, DDIM, 12);
}

// Round 13
// 617.419 us; speedup vs baseline: 1.0123x; 1.0123x over previous
//
#include <hip/hip_runtime.h>
#include <math.h>

#define BB 32
#define NN 1025
#define DDIM 768
#define HH 12
#define DHD 64
#define KC 257
#define CPBH 32

#define BT_K 320
#define BT_N 1088
#define SCALE_LOG2E 0.18033688011112042f  /* 0.125 * log2(e) */

typedef unsigned int u32;
typedef unsigned short u16;
typedef unsigned char u8;
typedef __attribute__((ext_vector_type(8))) short s8v;
typedef __attribute__((ext_vector_type(4))) float f4v;

__device__ __forceinline__ u16 f2bf(float f) {
  union { float f; u32 u; } v; v.f = f;
  return (u16)((v.u + 0x7fffu + ((v.u >> 16) & 1u)) >> 16);
}
__device__ __forceinline__ float bf2f(u16 h) {
  union { u32 u; float f; } v; v.u = ((u32)h) << 16;
  return v.f;
}
__device__ __forceinline__ void gload16(const u16* g, u16* l) {
  __builtin_amdgcn_global_load_lds((const __attribute__((address_space(1))) void*)g,
                                   (__attribute__((address_space(3))) void*)l, 16, 0, 0);
}

// ---------------------------------------------------------------------------
// fp32 -> bf16 cast (8 elements/thread)
// ---------------------------------------------------------------------------
__global__ __launch_bounds__(256) void cast_bf16_kernel(const float* __restrict__ s,
                                                        u16* __restrict__ d, int n8) {
  const int i = blockIdx.x * 256 + threadIdx.x;
  if (i >= n8) return;
  const float4 f0 = ((const float4*)s)[2 * i];
  const float4 f1 = ((const float4*)s)[2 * i + 1];
  s8v o;
  o[0] = (short)f2bf(f0.x); o[1] = (short)f2bf(f0.y);
  o[2] = (short)f2bf(f0.z); o[3] = (short)f2bf(f0.w);
  o[4] = (short)f2bf(f1.x); o[5] = (short)f2bf(f1.y);
  o[6] = (short)f2bf(f1.z); o[7] = (short)f2bf(f1.w);
  *(s8v*)&d[8 * (size_t)i] = o;
}

// fp32 -> (bf16 hi, bf16 lo) split cast
__global__ __launch_bounds__(256) void split_bf16_kernel(const float* __restrict__ s,
                                                         u16* __restrict__ dh,
                                                         u16* __restrict__ dl, int n8) {
  const int i = blockIdx.x * 256 + threadIdx.x;
  if (i >= n8) return;
  s8v oh, ol;
#pragma unroll
  for (int j = 0; j < 8; j++) {
    const float f = s[8 * (size_t)i + j];
    const u16 hb = f2bf(f);
    oh[j] = (short)hb;
    ol[j] = (short)f2bf(f - bf2f(hb));
  }
  *(s8v*)&dh[8 * (size_t)i] = oh;
  *(s8v*)&dl[8 * (size_t)i] = ol;
}

// ---------------------------------------------------------------------------
// tiled softmax pooling -> ctx [B, KC, D] (bf16 out). v2 (round 11, proven
// ~-13us): 256 thr (4 waves, one kk-tile per wave), float4 reads.
// ---------------------------------------------------------------------------
__global__ __launch_bounds__(256) void pool_ctx_kernel(const float* __restrict__ x,
                                                       const float* __restrict__ wlog,
                                                       u16* __restrict__ ctx) {
  const int w = threadIdx.x >> 6, lane = threadIdx.x & 63;
  const int bid = blockIdx.x;
  const int b = bid / 65;
  const int kk = (bid % 65) * 4 + w;
  if (kk >= KC) return;
  const float* xb = x + (size_t)b * NN * DDIM;
  u16* cout = ctx + ((size_t)b * KC + kk) * DDIM;
  if (kk == 0) {
#pragma unroll
    for (int u = lane; u < 192; u += 64) {
      const float4 f = ((const float4*)xb)[u];
      ushort4 o = {f2bf(f.x), f2bf(f.y), f2bf(f.z), f2bf(f.w)};
      *(ushort4*)&cout[u * 4] = o;
    }
    return;
  }
  const int t = kk - 1;
  const int gy = t >> 4, gx = t & 15;
  const int r0 = 1 + gy * 64 + gx * 2;
  const float* xr0 = xb + (size_t)r0 * DDIM;
  float s0 = 0.f, s1 = 0.f, s2 = 0.f, s3 = 0.f;
#pragma unroll
  for (int u = lane; u < 192; u += 64) {
    const float4 a = ((const float4*)xr0)[u];
    const float4 bq = ((const float4*)(xr0 + DDIM))[u];
    const float4 c = ((const float4*)(xr0 + 32 * DDIM))[u];
    const float4 d = ((const float4*)(xr0 + 33 * DDIM))[u];
    const float4 wv = ((const float4*)wlog)[u];
    s0 = fmaf(a.x, wv.x, fmaf(a.y, wv.y, fmaf(a.z, wv.z, fmaf(a.w, wv.w, s0))));
    s1 = fmaf(bq.x, wv.x, fmaf(bq.y, wv.y, fmaf(bq.z, wv.z, fmaf(bq.w, wv.w, s1))));
    s2 = fmaf(c.x, wv.x, fmaf(c.y, wv.y, fmaf(c.z, wv.z, fmaf(c.w, wv.w, s2))));
    s3 = fmaf(d.x, wv.x, fmaf(d.y, wv.y, fmaf(d.z, wv.z, fmaf(d.w, wv.w, s3))));
  }
#pragma unroll
  for (int off = 32; off; off >>= 1) {
    s0 += __shfl_xor(s0, off);
    s1 += __shfl_xor(s1, off);
    s2 += __shfl_xor(s2, off);
    s3 += __shfl_xor(s3, off);
  }
  const float m = fmaxf(fmaxf(s0, s1), fmaxf(s2, s3));
  float e0 = expf(s0 - m), e1 = expf(s1 - m), e2 = expf(s2 - m), e3 = expf(s3 - m);
  const float inv = 1.0f / (e0 + e1 + e2 + e3);
  e0 *= inv; e1 *= inv; e2 *= inv; e3 *= inv;
#pragma unroll
  for (int u = lane; u < 192; u += 64) {
    const float4 a = ((const float4*)xr0)[u];
    const float4 bq = ((const float4*)(xr0 + DDIM))[u];
    const float4 c = ((const float4*)(xr0 + 32 * DDIM))[u];
    const float4 d = ((const float4*)(xr0 + 33 * DDIM))[u];
    ushort4 o;
    o.x = f2bf(e0 * a.x + e1 * bq.x + e2 * c.x + e3 * d.x);
    o.y = f2bf(e0 * a.y + e1 * bq.y + e2 * c.y + e3 * d.y);
    o.z = f2bf(e0 * a.z + e1 * bq.z + e2 * c.z + e3 * d.z);
    o.w = f2bf(e0 * a.w + e1 * bq.w + e2 * c.w + e3 * d.w);
    *(ushort4*)&cout[u * 4] = o;
  }
}

// ---------------------------------------------------------------------------
// CPB bias, transposed+padded layout: biasT[h][k=320][n=1088] fp32,
// value = (mlp(feats)+b2)*mask*log2e for valid (k<257,n<1025), else -1e30.
// Thread idx = k*1088 + n -> coalesced stores.
// ---------------------------------------------------------------------------
__global__ __launch_bounds__(256) void cpb_biasT_kernel(const float* __restrict__ feats,
                                                        const float* __restrict__ mask,
                                                        const float* __restrict__ w1,
                                                        const float* __restrict__ b1,
                                                        const float* __restrict__ w2,
                                                        const float* __restrict__ b2,
                                                        float* __restrict__ biasT) {
  const int idx = blockIdx.x * 256 + threadIdx.x;
  if (idx >= BT_K * BT_N) return;
  const int k = idx / BT_N;
  const int n = idx - k * BT_N;
  const bool valid = (k < KC) && (n < NN);
  float out[HH];
  if (valid) {
    const float2 f = *(const float2*)&feats[2 * ((size_t)n * KC + k)];
    const float mk = mask[(size_t)n * KC + k] * 1.4426950408889634f;
    float hb[CPBH];
#pragma unroll
    for (int j = 0; j < CPBH; j++) {
      const float tv = fmaf(w1[2 * j], f.x, fmaf(w1[2 * j + 1], f.y, b1[j]));
      hb[j] = 0.5f * tv * (1.0f + erff(tv * 0.70710678118654752f));
    }
#pragma unroll
    for (int h = 0; h < HH; h++) {
      float acc = b2[h];
#pragma unroll
      for (int j = 0; j < CPBH; j++) acc = fmaf(hb[j], w2[h * CPBH + j], acc);
      out[h] = acc * mk;
    }
  } else {
#pragma unroll
    for (int h = 0; h < HH; h++) out[h] = -1.0e30f;
  }
#pragma unroll
  for (int h = 0; h < HH; h++) biasT[(size_t)h * BT_K * BT_N + idx] = out[h];
}

// ---------------------------------------------------------------------------
// bf16 MFMA GEMM, per-instantiation buffering (round 13): rounds 10-12 A/B
// matrix showed dbuf HELPS non-split (32.8 KB LDS keeps 4 blocks/CU,
// barrier-halving wins ~19us) but HURTS split (49.2 KB -> 3 blocks/CU,
// occupancy 38->29%, +13us). DBUF template param selects per launch.
// ---------------------------------------------------------------------------
template <int SPLIT, int DBUF, int WRITE_BF16, int ADD_BIAS>
__global__ __launch_bounds__(256) void gemm_mfma(const u16* __restrict__ Ah,
                                                 const u16* __restrict__ Al,
                                                 const u16* __restrict__ Bh,
                                                 const u16* __restrict__ Bl,
                                                 const float* __restrict__ bias,
                                                 float* __restrict__ Cf,
                                                 u16* __restrict__ Cb, int M, int Nout,
                                                 int nNB) {
  constexpr int BN = SPLIT ? 64 : 128;
  constexpr int NTI = SPLIT ? 2 : 4;
  constexpr int NBUF = DBUF ? 2 : 1;
  __shared__ u16 AhL[NBUF][128 * 32];
  __shared__ u16 BhL[NBUF][BN * 32];
  __shared__ u16 AlL[NBUF][SPLIT ? 128 * 32 : 8];
  __shared__ u16 BlL[NBUF][SPLIT ? BN * 32 : 8];
  const int tid = threadIdx.x;
  const int w = tid >> 6, l = tid & 63;
  const int lane16 = l & 15, quad = l >> 4;
  // ---- bijective XCD chunk swizzle ----
  const int nwg = (int)gridDim.x;
  const int q8 = nwg >> 3, r8 = nwg & 7;
  const int xcd = (int)blockIdx.x & 7, idx8 = (int)blockIdx.x >> 3;
  const int orig = (xcd < r8 ? xcd * (q8 + 1) : r8 * (q8 + 1) + (xcd - r8) * q8) + idx8;
  const int mb = orig / nNB;
  const int nb = orig - mb * nNB;
  const int m0 = mb * 128, n0 = nb * BN;
  const int sr = l >> 2, sc = (l & 3) * 8;
  const int ar0 = min(m0 + w * 32 + sr, M - 1);
  const int ar1 = min(m0 + w * 32 + 16 + sr, M - 1);
  const u16* ap0 = Ah + (size_t)ar0 * DDIM + sc;
  const u16* ap1 = Ah + (size_t)ar1 * DDIM + sc;
  const u16* alp0 = nullptr; const u16* alp1 = nullptr;
  const u16* bp0 = nullptr; const u16* bp1 = nullptr; const u16* blp0 = nullptr;
  if constexpr (SPLIT) {
    alp0 = Al + (size_t)ar0 * DDIM + sc;
    alp1 = Al + (size_t)ar1 * DDIM + sc;
    bp0 = Bh + (size_t)(n0 + w * 16 + sr) * DDIM + sc;
    blp0 = Bl + (size_t)(n0 + w * 16 + sr) * DDIM + sc;
  } else {
    bp0 = Bh + (size_t)(n0 + w * 32 + sr) * DDIM + sc;
    bp1 = Bh + (size_t)(n0 + w * 32 + 16 + sr) * DDIM + sc;
  }
  f4v acc[4][NTI];
#pragma unroll
  for (int mt = 0; mt < 4; mt++)
#pragma unroll
    for (int nt = 0; nt < NTI; nt++) acc[mt][nt] = (f4v){0.f, 0.f, 0.f, 0.f};
  const int mh = (w & 1) * 64;
  const int nh = (w >> 1) * (SPLIT ? 32 : 64);

  auto stage = [&](int buf, int k0) {
    gload16(ap0 + k0, &AhL[buf][(w * 32) * 32]);
    gload16(ap1 + k0, &AhL[buf][(w * 32 + 16) * 32]);
    if constexpr (SPLIT) {
      gload16(alp0 + k0, &AlL[buf][(w * 32) * 32]);
      gload16(alp1 + k0, &AlL[buf][(w * 32 + 16) * 32]);
      gload16(bp0 + k0, &BhL[buf][(w * 16) * 32]);
      gload16(blp0 + k0, &BlL[buf][(w * 16) * 32]);
    } else {
      gload16(bp0 + k0, &BhL[buf][(w * 32) * 32]);
      gload16(bp1 + k0, &BhL[buf][(w * 32 + 16) * 32]);
    }
  };
  auto compute = [&](int buf) {
    s8v af[4], afl[4];
#pragma unroll
    for (int mt = 0; mt < 4; mt++) {
      af[mt] = *(const s8v*)&AhL[buf][(mh + mt * 16 + lane16) * 32 + quad * 8];
      if constexpr (SPLIT)
        afl[mt] = *(const s8v*)&AlL[buf][(mh + mt * 16 + lane16) * 32 + quad * 8];
    }
#pragma unroll
    for (int nt = 0; nt < NTI; nt++) {
      const s8v bfh = *(const s8v*)&BhL[buf][(nh + nt * 16 + lane16) * 32 + quad * 8];
      s8v bfl;
      if constexpr (SPLIT)
        bfl = *(const s8v*)&BlL[buf][(nh + nt * 16 + lane16) * 32 + quad * 8];
#pragma unroll
      for (int mt = 0; mt < 4; mt++) {
        acc[mt][nt] = __builtin_amdgcn_mfma_f32_16x16x32_bf16(af[mt], bfh, acc[mt][nt], 0, 0, 0);
        if constexpr (SPLIT) {
          acc[mt][nt] = __builtin_amdgcn_mfma_f32_16x16x32_bf16(afl[mt], bfh, acc[mt][nt], 0, 0, 0);
          acc[mt][nt] = __builtin_amdgcn_mfma_f32_16x16x32_bf16(af[mt], bfl, acc[mt][nt], 0, 0, 0);
        }
      }
    }
  };

  if constexpr (DBUF) {
    stage(0, 0);
    __syncthreads();
    int cur = 0;
    for (int k0 = 0; k0 < DDIM; k0 += 32) {
      const int kn = k0 + 32;
      if (kn < DDIM) stage(cur ^ 1, kn);
      compute(cur);
      __syncthreads();
      cur ^= 1;
    }
  } else {
    for (int k0 = 0; k0 < DDIM; k0 += 32) {
      __syncthreads();
      stage(0, k0);
      __syncthreads();
      compute(0);
    }
  }
#pragma unroll
  for (int mt = 0; mt < 4; mt++)
#pragma unroll
    for (int nt = 0; nt < NTI; nt++)
#pragma unroll
      for (int r = 0; r < 4; r++) {
        const int row = m0 + mh + mt * 16 + quad * 4 + r;
        if (row < M) {
          const int col = n0 + nh + nt * 16 + lane16;
          float v = acc[mt][nt][r];
          if (ADD_BIAS) v += bias[col];
          if (WRITE_BF16) Cb[(size_t)row * Nout + col] = f2bf(v);
          else Cf[(size_t)row * Nout + col] = v;
        }
      }
}

// ---------------------------------------------------------------------------
// V transpose: kvb V-half [b][k][h*64+c] -> vt [b][h][c][k pad 320] bf16,
// zero-filled for k >= 257. Coalesced b128 reads, 16B-run scatter writes.
// ---------------------------------------------------------------------------
__global__ __launch_bounds__(256) void transpose_v_kernel(const u16* __restrict__ kvb,
                                                          u16* __restrict__ vt) {
  const int bh = blockIdx.x;
  const int b = bh / HH, h = bh % HH;
  const int tid = threadIdx.x;
  const int kk = tid >> 3;           // 0..31
  const int c0 = (tid & 7) * 8;      // 0..56
  u16* dbase = vt + (((size_t)b * HH + h) * 64 + c0) * BT_K;
#pragma unroll
  for (int ch = 0; ch < 10; ch++) {
    const int k = ch * 32 + kk;
    s8v v = {0, 0, 0, 0, 0, 0, 0, 0};
    if (k < KC)
      v = *(const s8v*)(kvb + ((size_t)b * KC + k) * (2 * DDIM) + DDIM + h * DHD + c0);
#pragma unroll
    for (int j = 0; j < 8; j++) dbase[(size_t)j * BT_K + k] = (u16)v[j];
  }
}

// ---------------------------------------------------------------------------
// MFMA attention v7 (round 10, proven): chunked K/V LDS staging via
// global_load_lds, XOR source-pre-swizzle, h-OUTER bijective XCD decode
// (keeps per-head biasT slice L2-resident).
// ---------------------------------------------------------------------------
#define PLS 72

__global__ __launch_bounds__(256, 4) void attn_mfma(const u16* qb,
                                                    const u16* __restrict__ kvb,
                                                    const u16* __restrict__ vt,
                                                    const float* __restrict__ biasT,
                                                    u16* oh, u16* __restrict__ ol) {
  __shared__ u16 KV[2][64 * 64];     // 16,384 B staging (K phase, then V phase)
  __shared__ u16 PL[4][16 * PLS];    //  9,216 B per-wave P tiles
  const int tid = threadIdx.x;
  const int w = tid >> 6, l = tid & 63;
  const int lane16 = l & 15, quad = l >> 4;
  const int r7 = lane16 & 7;
  // ---- bijective XCD chunk swizzle, h-OUTER decode (b inner, nb fastest) ----
  const int nwg = (int)gridDim.x;
  const int q8 = nwg >> 3, r8 = nwg & 7;
  const int xcd = (int)blockIdx.x & 7, idx8 = (int)blockIdx.x >> 3;
  const int orig = (xcd < r8 ? xcd * (q8 + 1) : r8 * (q8 + 1) + (xcd - r8) * q8) + idx8;
  const int nb = orig % 17;
  const int hb = orig / 17;
  const int b = hb % BB, h = hb / BB;
  const int n_base = nb * 64 + w * 16;

  const u16* kvb_bh = kvb + (size_t)b * KC * (2 * DDIM) + h * DHD;
  const u16* vt_bh = vt + (((size_t)b * HH + h) * 64) * BT_K;

  // staging lane geometry: each 1KB wave-load covers 8 rows x 128B;
  // lane l -> row +(l>>3), 16B-unit (l&7); source col16 XOR-swizzled by row&7.
  const int srow = l >> 3;                    // 0..7
  const int scol = ((l & 7) ^ srow) * 8;      // elem offset of swizzled 16B unit
  const int rbase = w * 16;                   // this wave's 16 rows of each chunk

  // ---- stage K chunk 0 ----
#pragma unroll
  for (int j = 0; j < 2; j++) {
    const int krow = min(rbase + j * 8 + srow, KC - 1);
    gload16(kvb_bh + (size_t)krow * (2 * DDIM) + scol, &KV[0][(rbase + j * 8) * 64]);
  }

  // ---- q fragments ----
  const int qrow = min(n_base + lane16, NN - 1);
  const u16* qp = qb + ((size_t)b * NN + qrow) * DDIM + h * DHD + quad * 8;
  const s8v qf0 = *(const s8v*)qp;
  const s8v qf1 = *(const s8v*)(qp + 32);

  __syncthreads();  // K ch0 staged

  // ---- S = QK^T fused with bias (log2 domain); K from LDS chunks ----
  f4v S[17];
  const float* bT = biasT + (size_t)h * BT_K * BT_N + (size_t)(n_base + quad * 4);
  float mx[4] = {-3.0e38f, -3.0e38f, -3.0e38f, -3.0e38f};
#pragma unroll
  for (int ch = 0; ch < 5; ch++) {
    if (ch < 4) {
#pragma unroll
      for (int j = 0; j < 2; j++) {
        const int krow = min((ch + 1) * 64 + rbase + j * 8 + srow, KC - 1);
        gload16(kvb_bh + (size_t)krow * (2 * DDIM) + scol,
                &KV[(ch + 1) & 1][(rbase + j * 8) * 64]);
      }
    }
    const u16* KL = KV[ch & 1];
#pragma unroll
    for (int tt = 0; tt < 4; tt++) {
      const int t = ch * 4 + tt;
      if (t < 17) {
        const int row = tt * 16 + lane16;
        const s8v kf0 = *(const s8v*)&KL[row * 64 + ((quad ^ r7) * 8)];
        const s8v kf1 = *(const s8v*)&KL[row * 64 + (((quad + 4) ^ r7) * 8)];
        f4v z = {0.f, 0.f, 0.f, 0.f};
        z = __builtin_amdgcn_mfma_f32_16x16x32_bf16(qf0, kf0, z, 0, 0, 0);
        z = __builtin_amdgcn_mfma_f32_16x16x32_bf16(qf1, kf1, z, 0, 0, 0);
        const float4 bv = *(const float4*)&bT[(size_t)(t * 16 + lane16) * BT_N];
        S[t][0] = fmaf(z[0], SCALE_LOG2E, bv.x);
        S[t][1] = fmaf(z[1], SCALE_LOG2E, bv.y);
        S[t][2] = fmaf(z[2], SCALE_LOG2E, bv.z);
        S[t][3] = fmaf(z[3], SCALE_LOG2E, bv.w);
#pragma unroll
        for (int r = 0; r < 4; r++) mx[r] = fmaxf(mx[r], S[t][r]);
      }
    }
    __syncthreads();
  }

  // ---- prefetch V chunk 0 (hides under softmax VALU, T14) ----
#pragma unroll
  for (int j = 0; j < 2; j++) {
    const int c = rbase + j * 8 + srow;
    gload16(vt_bh + (size_t)c * BT_K + scol, &KV[0][(rbase + j * 8) * 64]);
  }

  // ---- softmax (log2 domain, deferred normalization) ----
#pragma unroll
  for (int r = 0; r < 4; r++) {
    mx[r] = fmaxf(mx[r], __shfl_xor(mx[r], 1));
    mx[r] = fmaxf(mx[r], __shfl_xor(mx[r], 2));
    mx[r] = fmaxf(mx[r], __shfl_xor(mx[r], 4));
    mx[r] = fmaxf(mx[r], __shfl_xor(mx[r], 8));
  }
  float sm[4] = {0.f, 0.f, 0.f, 0.f};
#pragma unroll
  for (int t = 0; t < 17; t++)
#pragma unroll
    for (int r = 0; r < 4; r++) {
      const float p = exp2f(S[t][r] - mx[r]);  // unnormalized
      S[t][r] = p;
      sm[r] += p;
    }
#pragma unroll
  for (int r = 0; r < 4; r++) {
    sm[r] += __shfl_xor(sm[r], 1);
    sm[r] += __shfl_xor(sm[r], 2);
    sm[r] += __shfl_xor(sm[r], 4);
    sm[r] += __shfl_xor(sm[r], 8);
    sm[r] = 1.0f / sm[r];
  }

  f4v O[4];
#pragma unroll
  for (int nt = 0; nt < 4; nt++) O[nt] = (f4v){0.f, 0.f, 0.f, 0.f};

  __syncthreads();  // V ch0 staged

  u16* PLw = PL[w];
#pragma unroll
  for (int ch = 0; ch < 5; ch++) {
    if (ch < 4) {
#pragma unroll
      for (int j = 0; j < 2; j++) {
        const int c = rbase + j * 8 + srow;
        gload16(vt_bh + (size_t)c * BT_K + (ch + 1) * 64 + scol,
                &KV[(ch + 1) & 1][(rbase + j * 8) * 64]);
      }
    }
#pragma unroll
    for (int tt = 0; tt < 4; tt++) {
      const int t = ch * 4 + tt;
#pragma unroll
      for (int r = 0; r < 4; r++) {
        float pv = 0.f;
        if (t < 17) pv = S[t][r];
        PLw[(quad * 4 + r) * PLS + tt * 16 + lane16] = f2bf(pv);
      }
    }
    const u16* VL = KV[ch & 1];
    // per-wave private PL: within-wave lgkmcnt ordering suffices, no barrier
#pragma unroll
    for (int ks = 0; ks < 2; ks++) {
      const s8v a = *(const s8v*)&PLw[lane16 * PLS + ks * 32 + quad * 8];
#pragma unroll
      for (int nt = 0; nt < 4; nt++) {
        const s8v bfr =
            *(const s8v*)&VL[(nt * 16 + lane16) * 64 + (((ks * 4 + quad) ^ r7) * 8)];
        O[nt] = __builtin_amdgcn_mfma_f32_16x16x32_bf16(a, bfr, O[nt], 0, 0, 0);
      }
    }
    __syncthreads();
  }

  // ---- epilogue: normalize + split-store (hi/lo bf16) ----
#pragma unroll
  for (int nt = 0; nt < 4; nt++)
#pragma unroll
    for (int r = 0; r < 4; r++) {
      const int n = n_base + quad * 4 + r;
      if (n < NN) {
        const size_t idx = ((size_t)b * NN + n) * DDIM + h * DHD + nt * 16 + lane16;
        const float v = O[nt][r] * sm[r];
        const u16 hb2 = f2bf(v);
        oh[idx] = hb2;
        ol[idx] = f2bf(v - bf2f(hb2));
      }
    }
}

// ---------------------------------------------------------------------------
extern "C" void kernel_launch(void* const* d_in, const int* in_sizes, int n_in,
                              void* d_out, int out_size, void* d_ws, size_t ws_size,
                              hipStream_t stream) {
  (void)in_sizes; (void)n_in; (void)out_size; (void)ws_size;
  const float* x    = (const float*)d_in[0];
  const float* wlog = (const float*)d_in[1];
  const float* Wq   = (const float*)d_in[2];
  const float* Wkv  = (const float*)d_in[3];
  const float* Wo   = (const float*)d_in[4];
  const float* bo   = (const float*)d_in[5];
  const float* w1   = (const float*)d_in[6];
  const float* b1   = (const float*)d_in[7];
  const float* w2   = (const float*)d_in[8];
  const float* b2   = (const float*)d_in[9];
  const float* feats = (const float*)d_in[10];
  const float* mask  = (const float*)d_in[11];
  float* out = (float*)d_out;

  u8* p = (u8*)d_ws;
  u16* xb    = (u16*)(p + 0);             // 50,380,800 B (later o_lo)
  u16* ctxb  = (u16*)(p + 50380800);      // 12,632,064
  u16* Wqb   = (u16*)(p + 63012864);      //  1,179,648
  u16* Wkvb  = (u16*)(p + 64192512);      //  2,359,296
  u16* Woh   = (u16*)(p + 66551808);      //  1,179,648
  u16* Wol   = (u16*)(p + 67731456);      //  1,179,648
  u16* qb    = (u16*)(p + 68911104);      // 50,380,800 (later o_hi)
  u16* kvb   = (u16*)(p + 119291904);     // 25,264,128
  u16* vt    = (u16*)(p + 144556032);     // 15,728,640  [B][H][64][320]
  float* biasT = (float*)(p + 160284672); // 16,711,680  [H][320][1088] -> ~177 MB

  const int nx8 = (BB * NN * DDIM) / 8;
  cast_bf16_kernel<<<dim3((nx8 + 255) / 256), dim3(256), 0, stream>>>(x, xb, nx8);
  cast_bf16_kernel<<<dim3(288), dim3(256), 0, stream>>>(Wq, Wqb, (DDIM * DDIM) / 8);
  cast_bf16_kernel<<<dim3(576), dim3(256), 0, stream>>>(Wkv, Wkvb, (2 * DDIM * DDIM) / 8);
  split_bf16_kernel<<<dim3(288), dim3(256), 0, stream>>>(Wo, Woh, Wol, (DDIM * DDIM) / 8);
  pool_ctx_kernel<<<dim3(BB * 65), dim3(256), 0, stream>>>(x, wlog, ctxb);
  cpb_biasT_kernel<<<dim3((BT_K * BT_N) / 256), dim3(256), 0, stream>>>(
      feats, mask, w1, b1, w2, b2, biasT);
  gemm_mfma<0, 1, 1, 0><<<dim3(257 * 6), dim3(256), 0, stream>>>(
      xb, nullptr, Wqb, nullptr, nullptr, nullptr, qb, BB * NN, DDIM, 6);
  gemm_mfma<0, 1, 1, 0><<<dim3(65 * 12), dim3(256), 0, stream>>>(
      ctxb, nullptr, Wkvb, nullptr, nullptr, nullptr, kvb, BB * KC, 2 * DDIM, 12);
  transpose_v_kernel<<<dim3(BB * HH), dim3(256), 0, stream>>>(kvb, vt);
  attn_mfma<<<dim3(17 * HH * BB), dim3(256), 0, stream>>>(qb, kvb, vt, biasT, qb, xb);
  gemm_mfma<1, 0, 0, 1><<<dim3(257 * 12), dim3(256), 0, stream>>>(
      qb, xb, Woh, Wol, bo, out, nullptr, BB * NN, DDIM, 12);
}